// Round 4
// baseline (766.301 us; speedup 1.0000x reference)
//
#include <hip/hip_runtime.h>
#include <hip/hip_bf16.h>

#define EPS_BN 1e-5f

constexpr int B  = 2048, F0 = 64, K = 14;
constexpr int C1 = 64,  F1 = 32;
constexpr int C2 = 128, F2 = 16;
constexpr int C3 = 256, F3 = 8;

typedef __attribute__((ext_vector_type(8))) short bf16x8;
typedef __attribute__((ext_vector_type(4))) float f32x4;

__device__ __forceinline__ float bf2f(unsigned short u) {
    union { unsigned int i; float f; } x; x.i = ((unsigned int)u) << 16; return x.f;
}
__device__ __forceinline__ unsigned short f2bf(float f) {
    union { float f; unsigned int i; } x; x.f = f;
    unsigned int r = (x.i + 0x7fffu + ((x.i >> 16) & 1u)) >> 16;
    return (unsigned short)r;
}

// DPP row_shl:1 (ctrl 0x101) within 16-lane rows, zero-fill (bound_ctrl).
// dest lane m <- src lane m+1  (row_shr:n = lane i-n -> i, per DPP scan idiom,
// so shl is the direction that pulls the NEXT k-position's fragment).
__device__ __forceinline__ bf16x8 dpp_shl1(bf16x8 v) {
    union { bf16x8 v; int i[4]; } a, r;
    a.v = v;
    #pragma unroll
    for (int j = 0; j < 4; ++j)
        r.i[j] = __builtin_amdgcn_update_dpp(0, a.i[j], 0x101, 0xf, 0xf, true);
    return r.v;
}

// ---- fold BN into conv1 weights (fp32, layout [c][2][9] flat) ----
__global__ void repack_w1(const float* __restrict__ w1, const float* __restrict__ g,
                          const float* __restrict__ bb, const float* __restrict__ m,
                          const float* __restrict__ v, float* __restrict__ w1f,
                          float* __restrict__ t1) {
    int i = blockIdx.x * 256 + threadIdx.x;
    if (i < C1) {
        float s = g[i] * rsqrtf(v[i] + EPS_BN);
        t1[i] = bb[i] - m[i] * s;
    }
    if (i < C1 * 2 * 9) {
        int c = i / 18;
        float s = g[c] * rsqrtf(v[c] + EPS_BN);
        w1f[i] = w1[i] * s;
    }
}

// ---- repack conv weights into MFMA B-fragment layout, bf16, BN-folded ----
// wp[((chunk*COUT + n)*32) + kk] = W[tap][ci][n]*s[n], chunk=tap*(CIN/32)+cc, ci=cc*32+kk
template<int CIN, int COUT>
__global__ void repack_mfma(const float* __restrict__ w, const float* __restrict__ g,
                            const float* __restrict__ bb, const float* __restrict__ m,
                            const float* __restrict__ v, unsigned short* __restrict__ wp,
                            float* __restrict__ t) {
    int idx = blockIdx.x * 256 + threadIdx.x;
    if (idx < COUT) {
        float s = g[idx] * rsqrtf(v[idx] + EPS_BN);
        t[idx] = bb[idx] - m[idx] * s;
    }
    if (idx < 9 * CIN * COUT) {
        constexpr int CCS = CIN / 32;
        int kk = idx & 31;
        int rest = idx >> 5;
        int n = rest & (COUT - 1);
        int chunk = rest / COUT;
        int tap = chunk / CCS;
        int cc  = chunk & (CCS - 1);
        int ci = cc * 32 + kk;
        float s = g[n] * rsqrtf(v[n] + EPS_BN);
        wp[idx] = f2bf(w[(n * CIN + ci) * 9 + tap] * s);
    }
}

// ---- conv1 (2->64, 3x3, stride (2,1), pad 1) + BN + ReLU, NHWC bf16 out ----
__global__ void conv1_kernel(const float* __restrict__ x, const float* __restrict__ sig,
                             const float* __restrict__ w1f, const float* __restrict__ t1,
                             unsigned short* __restrict__ h1) {
    __shared__ float xs[F0 * K], ssg[F0 * K], wsh[C1 * 19], bsh[C1];
    int b = blockIdx.x, t = threadIdx.x;
    for (int i = t; i < F0 * K; i += 256) {
        xs[i]  = x[(size_t)b * F0 * K + i];
        ssg[i] = sig[(size_t)b * F0 * K + i] * 10.0f;
    }
    for (int i = t; i < C1 * 18; i += 256) {
        int c = i / 18, r = i % 18;
        wsh[c * 19 + r] = w1f[i];
    }
    if (t < C1) bsh[t] = t1[t];
    __syncthreads();
    int c = t & 63, pg = t >> 6;
    for (int p = pg; p < F1 * K; p += 4) {
        int f = p / K, k = p % K;
        float acc = bsh[c];
        #pragma unroll
        for (int df = 0; df < 3; ++df) {
            int fi = 2 * f + df - 1;
            if (fi < 0 || fi >= F0) continue;
            #pragma unroll
            for (int dk = 0; dk < 3; ++dk) {
                int ki = k + dk - 1;
                if (ki < 0 || ki >= K) continue;
                acc = fmaf(xs[fi * K + ki],  wsh[c * 19 + df * 3 + dk], acc);
                acc = fmaf(ssg[fi * K + ki], wsh[c * 19 + 9 + df * 3 + dk], acc);
            }
        }
        h1[(((size_t)b * F1 + f) * K + k) * C1 + c] = f2bf(fmaxf(acc, 0.f));
    }
}

// ---- conv2/conv3 as MFMA GEMM, dedup row staging + DPP tap-shift ----
// Block: 4 waves, G=4 (f2) groups. LDS: 9 planes (fi = 2*f2base-1+pi), 16 k-slots
// (p=kin+1, zeros at p=0,15), chunk index rotated by p for bank spread.
// Wave: all 4 groups x (COUT/4) cols. dk=1,2 A-frags via DPP row_shl of dk=0.
template<int CIN, int COUT, int FIN, int MINB>
__launch_bounds__(256, MINB)
__global__ void conv_mfma(const unsigned short* __restrict__ hin,
                          const unsigned short* __restrict__ wp,
                          const float* __restrict__ tb,
                          unsigned short* __restrict__ hout) {
    constexpr int G = 4;
    constexpr int NT = COUT / 64;        // n-tiles per wave
    constexpr int CCS = CIN / 32;        // 32-ci chunks (MFMA K)
    constexpr int CH = CIN / 8;          // 16B chunks per row
    __shared__ alignas(16) unsigned short lin[9 * 16 * CIN];

    const int b = blockIdx.y;
    const int f2base = blockIdx.x * G;
    const int t = threadIdx.x;

    for (int i = t; i < 9 * 16 * CIN / 8; i += 256)
        ((uint4*)lin)[i] = uint4{0, 0, 0, 0};
    __syncthreads();

    for (int i = t; i < 9 * 14 * CH; i += 256) {
        int c = i & (CH - 1);
        int r = i / CH;
        int kin = r % 14, pi = r / 14;
        int fi = 2 * f2base - 1 + pi;
        if (fi >= 0 && fi < FIN) {
            uint4 val = *(const uint4*)(hin + ((size_t)(b * FIN + fi) * K + kin) * CIN + c * 8);
            int slot = (c + kin + 1) & (CH - 1);
            *(uint4*)(&lin[((pi * 16) + kin + 1) * CIN + slot * 8]) = val;
        }
    }
    __syncthreads();

    const int lane = t & 63;
    const int wave = t >> 6;
    const int m = lane & 15;             // A row (kout) / B col
    const int q = lane >> 4;
    const int nBase = wave * (COUT / 4);

    f32x4 acc[G][NT];
    #pragma unroll
    for (int nt = 0; nt < NT; ++nt) {
        float bias = tb[nBase + nt * 16 + m];
        #pragma unroll
        for (int g = 0; g < G; ++g)
            acc[g][nt] = f32x4{bias, bias, bias, bias};
    }

    #pragma unroll
    for (int df = 0; df < 3; ++df) {
        #pragma unroll
        for (int cc = 0; cc < CCS; ++cc) {
            bf16x8 bv[3][NT];
            #pragma unroll
            for (int dk = 0; dk < 3; ++dk) {
                const int chunk = (df * 3 + dk) * CCS + cc;
                #pragma unroll
                for (int nt = 0; nt < NT; ++nt)
                    bv[dk][nt] = *(const bf16x8*)(wp + ((chunk * COUT + nBase + nt * 16 + m) << 5) + q * 8);
            }
            #pragma unroll
            for (int g = 0; g < G; ++g) {
                // dk=0 frag: rows p=m (kin=m-1), rotated chunk index
                const unsigned short* ap =
                    lin + ((2 * g + df) * 16 + m) * CIN + ((cc * 4 + q + m) & (CH - 1)) * 8;
                bf16x8 a0 = *(const bf16x8*)ap;
                bf16x8 a1 = dpp_shl1(a0);
                bf16x8 a2 = dpp_shl1(a1);
                #pragma unroll
                for (int nt = 0; nt < NT; ++nt)
                    acc[g][nt] = __builtin_amdgcn_mfma_f32_16x16x32_bf16(a0, bv[0][nt], acc[g][nt], 0, 0, 0);
                #pragma unroll
                for (int nt = 0; nt < NT; ++nt)
                    acc[g][nt] = __builtin_amdgcn_mfma_f32_16x16x32_bf16(a1, bv[1][nt], acc[g][nt], 0, 0, 0);
                #pragma unroll
                for (int nt = 0; nt < NT; ++nt)
                    acc[g][nt] = __builtin_amdgcn_mfma_f32_16x16x32_bf16(a2, bv[2][nt], acc[g][nt], 0, 0, 0);
            }
        }
    }

    #pragma unroll
    for (int g = 0; g < G; ++g) {
        size_t rowbase = ((size_t)(b * (FIN / 2) + f2base + g)) * K;
        #pragma unroll
        for (int nt = 0; nt < NT; ++nt) {
            int col = nBase + nt * 16 + m;
            #pragma unroll
            for (int i = 0; i < 4; ++i) {
                int row = q * 4 + i;
                if (row < K)
                    hout[(rowbase + row) * COUT + col] = f2bf(fmaxf(acc[g][nt][i], 0.f));
            }
        }
    }
}

// ---- conv4 (256->2, kernel (8,1)) + transpose to [B,K,2] ----
__global__ void conv4_kernel(const unsigned short* __restrict__ h3,
                             const float* __restrict__ w4, float* __restrict__ out) {
    int b = blockIdx.x;
    int t = threadIdx.x;   // 256 = C3
    float wa[8], wb[8];
    #pragma unroll
    for (int f = 0; f < 8; ++f) {
        wa[f] = w4[(0 * C3 + t) * 8 + f];
        wb[f] = w4[(1 * C3 + t) * 8 + f];
    }
    float p0[K], p1[K];
    #pragma unroll
    for (int k = 0; k < K; ++k) { p0[k] = 0.f; p1[k] = 0.f; }
    for (int f = 0; f < 8; ++f) {
        #pragma unroll
        for (int k = 0; k < K; ++k) {
            float v = bf2f(h3[((size_t)(b * F3 + f) * K + k) * C3 + t]);
            p0[k] = fmaf(v, wa[f], p0[k]);
            p1[k] = fmaf(v, wb[f], p1[k]);
        }
    }
    __shared__ float red[4][2 * K];
    int lane = t & 63, wv = t >> 6;
    #pragma unroll
    for (int k = 0; k < K; ++k) {
        float a = p0[k], c = p1[k];
        #pragma unroll
        for (int off = 32; off > 0; off >>= 1) {
            a += __shfl_down(a, off, 64);
            c += __shfl_down(c, off, 64);
        }
        if (lane == 0) { red[wv][k * 2 + 0] = a; red[wv][k * 2 + 1] = c; }
    }
    __syncthreads();
    if (t < 2 * K) {
        out[b * (2 * K) + t] = red[0][t] + red[1][t] + red[2][t] + red[3][t];
    }
}

extern "C" void kernel_launch(void* const* d_in, const int* in_sizes, int n_in,
                              void* d_out, int out_size, void* d_ws, size_t ws_size,
                              hipStream_t stream) {
    const float* x   = (const float*)d_in[0];
    const float* sig = (const float*)d_in[1];
    const float* w1  = (const float*)d_in[2];
    const float* w2  = (const float*)d_in[3];
    const float* w3  = (const float*)d_in[4];
    const float* w4  = (const float*)d_in[5];
    const float* g1  = (const float*)d_in[6];
    const float* b1  = (const float*)d_in[7];
    const float* m1  = (const float*)d_in[8];
    const float* v1  = (const float*)d_in[9];
    const float* g2  = (const float*)d_in[10];
    const float* b2  = (const float*)d_in[11];
    const float* m2  = (const float*)d_in[12];
    const float* v2  = (const float*)d_in[13];
    const float* g3  = (const float*)d_in[14];
    const float* b3  = (const float*)d_in[15];
    const float* m3  = (const float*)d_in[16];
    const float* v3  = (const float*)d_in[17];

    char* ws = (char*)d_ws;
    size_t off = 0;
    auto alloc = [&](size_t bytes) {
        char* p = ws + off;
        off += (bytes + 255) & ~(size_t)255;
        return p;
    };
    unsigned short* h1  = (unsigned short*)alloc((size_t)B * F1 * K * C1 * 2);  // reused as h3
    unsigned short* h2  = (unsigned short*)alloc((size_t)B * F2 * K * C2 * 2);
    float* w1f = (float*)alloc((size_t)C1 * 2 * 9 * 4);
    float* t1  = (float*)alloc((size_t)C1 * 4);
    unsigned short* wp2 = (unsigned short*)alloc((size_t)9 * C1 * C2 * 2);
    float* t2  = (float*)alloc((size_t)C2 * 4);
    unsigned short* wp3 = (unsigned short*)alloc((size_t)9 * C2 * C3 * 2);
    float* t3  = (float*)alloc((size_t)C3 * 4);
    unsigned short* h3 = h1;

    repack_w1<<<(C1 * 2 * 9 + 255) / 256, 256, 0, stream>>>(w1, g1, b1, m1, v1, w1f, t1);
    repack_mfma<C1, C2><<<(9 * C1 * C2 + 255) / 256, 256, 0, stream>>>(w2, g2, b2, m2, v2, wp2, t2);
    repack_mfma<C2, C3><<<(9 * C2 * C3 + 255) / 256, 256, 0, stream>>>(w3, g3, b3, m3, v3, wp3, t3);

    conv1_kernel<<<B, 256, 0, stream>>>(x, sig, w1f, t1, h1);
    conv_mfma<C1, C2, F1, 4><<<dim3(F2 / 4, B), 256, 0, stream>>>(h1, wp2, t2, h2);
    conv_mfma<C2, C3, F2, 3><<<dim3(F3 / 4, B), 256, 0, stream>>>(h2, wp3, t3, h3);
    conv4_kernel<<<B, 256, 0, stream>>>(h3, w4, (float*)d_out);
}

// Round 5
// 655.392 us; speedup vs baseline: 1.1692x; 1.1692x over previous
//
#include <hip/hip_runtime.h>
#include <hip/hip_bf16.h>

#define EPS_BN 1e-5f

constexpr int B  = 2048, F0 = 64, K = 14;
constexpr int C1 = 64,  F1 = 32;
constexpr int C2 = 128, F2 = 16;
constexpr int C3 = 256, F3 = 8;

typedef __attribute__((ext_vector_type(8))) short bf16x8;
typedef __attribute__((ext_vector_type(4))) float f32x4;

__device__ __forceinline__ float bf2f(unsigned short u) {
    union { unsigned int i; float f; } x; x.i = ((unsigned int)u) << 16; return x.f;
}
__device__ __forceinline__ unsigned short f2bf(float f) {
    union { float f; unsigned int i; } x; x.f = f;
    unsigned int r = (x.i + 0x7fffu + ((x.i >> 16) & 1u)) >> 16;
    return (unsigned short)r;
}

// DPP row_shl:1 (ctrl 0x101), zero-fill: dest lane m <- src lane m+1 (16-lane rows).
__device__ __forceinline__ bf16x8 dpp_shl1(bf16x8 v) {
    union { bf16x8 v; int i[4]; } a, r;
    a.v = v;
    #pragma unroll
    for (int j = 0; j < 4; ++j)
        r.i[j] = __builtin_amdgcn_update_dpp(0, a.i[j], 0x101, 0xf, 0xf, true);
    return r.v;
}

// ---- fold BN into conv1 weights ----
__global__ void repack_w1(const float* __restrict__ w1, const float* __restrict__ g,
                          const float* __restrict__ bb, const float* __restrict__ m,
                          const float* __restrict__ v, float* __restrict__ w1f,
                          float* __restrict__ t1) {
    int i = blockIdx.x * 256 + threadIdx.x;
    if (i < C1) {
        float s = g[i] * rsqrtf(v[i] + EPS_BN);
        t1[i] = bb[i] - m[i] * s;
    }
    if (i < C1 * 2 * 9) {
        int c = i / 18;
        float s = g[c] * rsqrtf(v[c] + EPS_BN);
        w1f[i] = w1[i] * s;
    }
}

// ---- repack conv weights into MFMA B-fragment layout, bf16, BN-folded ----
template<int CIN, int COUT>
__global__ void repack_mfma(const float* __restrict__ w, const float* __restrict__ g,
                            const float* __restrict__ bb, const float* __restrict__ m,
                            const float* __restrict__ v, unsigned short* __restrict__ wp,
                            float* __restrict__ t) {
    int idx = blockIdx.x * 256 + threadIdx.x;
    if (idx < COUT) {
        float s = g[idx] * rsqrtf(v[idx] + EPS_BN);
        t[idx] = bb[idx] - m[idx] * s;
    }
    if (idx < 9 * CIN * COUT) {
        constexpr int CCS = CIN / 32;
        int kk = idx & 31;
        int rest = idx >> 5;
        int n = rest & (COUT - 1);
        int chunk = rest / COUT;
        int tap = chunk / CCS;
        int cc  = chunk & (CCS - 1);
        int ci = cc * 32 + kk;
        float s = g[n] * rsqrtf(v[n] + EPS_BN);
        wp[idx] = f2bf(w[(n * CIN + ci) * 9 + tap] * s);
    }
}

__global__ void zero_out(float* __restrict__ out) {
    int i = blockIdx.x * 256 + threadIdx.x;
    if (i < B * K * 2) out[i] = 0.f;
}

// ---- fully fused conv1+conv2+conv3+conv4 ----
// Block (h, b): h selects output half (conv3 rows 4h..4h+3). Intermediates in LDS.
__launch_bounds__(256, 2)
__global__ void fused_all(const float* __restrict__ x, const float* __restrict__ sig,
                          const float* __restrict__ w1f, const float* __restrict__ t1,
                          const unsigned short* __restrict__ wp2, const float* __restrict__ t2,
                          const unsigned short* __restrict__ wp3, const float* __restrict__ t3,
                          const float* __restrict__ w4, float* __restrict__ out) {
    __shared__ alignas(16) unsigned short s2l[19 * 16 * 64];   // conv1 out (h1 planes, rotated)
    __shared__ alignas(16) unsigned short s3l[9 * 16 * 128];   // conv2 out (h2 planes, rotated); x/sig overlay
    __shared__ float red[4][4][4][2];

    const int h = blockIdx.x, b = blockIdx.y, t = threadIdx.x;
    const int lane = t & 63, wave = t >> 6;
    const int m = lane & 15, q = lane >> 4;

    // ph0: zero s2, stage x/sig (overlaid on s3)
    float* xs = (float*)s3l;
    float* ss = xs + F0 * K;
    for (int i = t; i < 19 * 16 * 64 / 8; i += 256) ((uint4*)s2l)[i] = uint4{0, 0, 0, 0};
    for (int i = t; i < F0 * K; i += 256) {
        xs[i] = x[(size_t)b * F0 * K + i];
        ss[i] = sig[(size_t)b * F0 * K + i] * 10.0f;
    }
    __syncthreads();

    // ph1: conv1 -> s2 (planes f1 = 16h-3 .. 16h+15)
    {
        const int c1 = t & 63;
        float wx[9], wg[9];
        #pragma unroll
        for (int r = 0; r < 9; ++r) { wx[r] = w1f[c1 * 18 + r]; wg[r] = w1f[c1 * 18 + 9 + r]; }
        const float bias = t1[c1];
        for (int pos = (t >> 6); pos < 19 * 14; pos += 4) {
            int pi = pos / 14, k = pos % 14;
            int f1 = pi + 16 * h - 3;
            if (f1 < 0 || f1 >= F1) continue;
            float acc = bias;
            #pragma unroll
            for (int df = 0; df < 3; ++df) {
                int fi = 2 * f1 + df - 1;
                if (fi < 0 || fi >= F0) continue;
                #pragma unroll
                for (int dk = 0; dk < 3; ++dk) {
                    int ki = k + dk - 1;
                    if (ki < 0 || ki >= K) continue;
                    acc = fmaf(xs[fi * K + ki], wx[df * 3 + dk], acc);
                    acc = fmaf(ss[fi * K + ki], wg[df * 3 + dk], acc);
                }
            }
            int p = k + 1;
            s2l[(pi * 16 + p) * 64 + (((c1 >> 3) + p) & 7) * 8 + (c1 & 7)] = f2bf(fmaxf(acc, 0.f));
        }
    }
    __syncthreads();

    // ph1b: zero s3 (kills x/sig overlay; provides pad slots + invalid-row zeros)
    for (int i = t; i < 9 * 16 * 128 / 8; i += 256) ((uint4*)s3l)[i] = uint4{0, 0, 0, 0};
    __syncthreads();

    // ph2: conv2 MFMA (9 h2 rows r = 8h-1 .. 8h+7) -> s3
    {
        const int nb = wave * 32;       // NT=2 cols per wave
        f32x4 acc2[9][2];
        #pragma unroll
        for (int nt = 0; nt < 2; ++nt) {
            float bz = t2[nb + nt * 16 + m];
            #pragma unroll
            for (int rr = 0; rr < 9; ++rr) acc2[rr][nt] = f32x4{bz, bz, bz, bz};
        }
        #pragma unroll
        for (int df = 0; df < 3; ++df)
        #pragma unroll
        for (int cc = 0; cc < 2; ++cc) {
            bf16x8 bv[3][2];
            #pragma unroll
            for (int dk = 0; dk < 3; ++dk) {
                int chunk = (df * 3 + dk) * 2 + cc;
                #pragma unroll
                for (int nt = 0; nt < 2; ++nt)
                    bv[dk][nt] = *(const bf16x8*)(wp2 + ((chunk * C2 + nb + nt * 16 + m) << 5) + q * 8);
            }
            #pragma unroll
            for (int rr = 0; rr < 9; ++rr) {
                const unsigned short* ap = s2l + ((2 * rr + df) * 16 + m) * 64 + ((cc * 4 + q + m) & 7) * 8;
                bf16x8 a0 = *(const bf16x8*)ap;
                bf16x8 a1 = dpp_shl1(a0);
                bf16x8 a2 = dpp_shl1(a1);
                #pragma unroll
                for (int nt = 0; nt < 2; ++nt)
                    acc2[rr][nt] = __builtin_amdgcn_mfma_f32_16x16x32_bf16(a0, bv[0][nt], acc2[rr][nt], 0, 0, 0);
                #pragma unroll
                for (int nt = 0; nt < 2; ++nt)
                    acc2[rr][nt] = __builtin_amdgcn_mfma_f32_16x16x32_bf16(a1, bv[1][nt], acc2[rr][nt], 0, 0, 0);
                #pragma unroll
                for (int nt = 0; nt < 2; ++nt)
                    acc2[rr][nt] = __builtin_amdgcn_mfma_f32_16x16x32_bf16(a2, bv[2][nt], acc2[rr][nt], 0, 0, 0);
            }
        }
        #pragma unroll
        for (int rr = 0; rr < 9; ++rr) {
            int r = rr + 8 * h - 1;
            if (r < 0 || r >= F2) continue;       // invalid rows stay zero
            #pragma unroll
            for (int nt = 0; nt < 2; ++nt) {
                int ch = nb + nt * 16 + m;
                int c = ch >> 3, sub = ch & 7;
                #pragma unroll
                for (int i = 0; i < 4; ++i) {
                    int kp = q * 4 + i;
                    if (kp >= K) continue;
                    int p = kp + 1;
                    s3l[(rr * 16 + p) * 128 + ((c + p) & 15) * 8 + sub] = f2bf(fmaxf(acc2[rr][nt][i], 0.f));
                }
            }
        }
    }
    __syncthreads();

    // ph3: conv3 MFMA (rows f3 = 4h+g) ; ph4: conv4 on accumulators
    {
        const int nb = wave * 64;       // NT=4 cols per wave
        f32x4 acc3[4][4];
        #pragma unroll
        for (int nt = 0; nt < 4; ++nt) {
            float bz = t3[nb + nt * 16 + m];
            #pragma unroll
            for (int g = 0; g < 4; ++g) acc3[g][nt] = f32x4{bz, bz, bz, bz};
        }
        #pragma unroll
        for (int df = 0; df < 3; ++df)
        #pragma unroll
        for (int cc = 0; cc < 4; ++cc) {
            bf16x8 bv[3][4];
            #pragma unroll
            for (int dk = 0; dk < 3; ++dk) {
                int chunk = (df * 3 + dk) * 4 + cc;
                #pragma unroll
                for (int nt = 0; nt < 4; ++nt)
                    bv[dk][nt] = *(const bf16x8*)(wp3 + ((chunk * C3 + nb + nt * 16 + m) << 5) + q * 8);
            }
            #pragma unroll
            for (int g = 0; g < 4; ++g) {
                const unsigned short* ap = s3l + ((2 * g + df) * 16 + m) * 128 + ((cc * 4 + q + m) & 15) * 8;
                bf16x8 a0 = *(const bf16x8*)ap;
                bf16x8 a1 = dpp_shl1(a0);
                bf16x8 a2 = dpp_shl1(a1);
                #pragma unroll
                for (int nt = 0; nt < 4; ++nt)
                    acc3[g][nt] = __builtin_amdgcn_mfma_f32_16x16x32_bf16(a0, bv[0][nt], acc3[g][nt], 0, 0, 0);
                #pragma unroll
                for (int nt = 0; nt < 4; ++nt)
                    acc3[g][nt] = __builtin_amdgcn_mfma_f32_16x16x32_bf16(a1, bv[1][nt], acc3[g][nt], 0, 0, 0);
                #pragma unroll
                for (int nt = 0; nt < 4; ++nt)
                    acc3[g][nt] = __builtin_amdgcn_mfma_f32_16x16x32_bf16(a2, bv[2][nt], acc3[g][nt], 0, 0, 0);
            }
        }
        // ph4: conv4 partials (ReLU + dot over (ch, f3) owned by this lane)
        float so[2][4] = {{0.f, 0.f, 0.f, 0.f}, {0.f, 0.f, 0.f, 0.f}};
        #pragma unroll
        for (int nt = 0; nt < 4; ++nt) {
            int ch = nb + nt * 16 + m;
            #pragma unroll
            for (int g = 0; g < 4; ++g) {
                int f3 = 4 * h + g;
                float wa = w4[(0 * C3 + ch) * 8 + f3];
                float wb = w4[(1 * C3 + ch) * 8 + f3];
                #pragma unroll
                for (int i = 0; i < 4; ++i) {
                    float vv = fmaxf(acc3[g][nt][i], 0.f);
                    so[0][i] = fmaf(vv, wa, so[0][i]);
                    so[1][i] = fmaf(vv, wb, so[1][i]);
                }
            }
        }
        #pragma unroll
        for (int off = 1; off < 16; off <<= 1)
            #pragma unroll
            for (int o = 0; o < 2; ++o)
                #pragma unroll
                for (int i = 0; i < 4; ++i)
                    so[o][i] += __shfl_xor(so[o][i], off, 64);
        if (m == 0) {
            #pragma unroll
            for (int i = 0; i < 4; ++i) {
                red[wave][q][i][0] = so[0][i];
                red[wave][q][i][1] = so[1][i];
            }
        }
    }
    __syncthreads();
    if (t < K * 2) {
        int k = t >> 1, o = t & 1;
        float v = red[0][k >> 2][k & 3][o] + red[1][k >> 2][k & 3][o]
                + red[2][k >> 2][k & 3][o] + red[3][k >> 2][k & 3][o];
        atomicAdd(&out[(b * K + k) * 2 + o], v);
    }
}

extern "C" void kernel_launch(void* const* d_in, const int* in_sizes, int n_in,
                              void* d_out, int out_size, void* d_ws, size_t ws_size,
                              hipStream_t stream) {
    const float* x   = (const float*)d_in[0];
    const float* sig = (const float*)d_in[1];
    const float* w1  = (const float*)d_in[2];
    const float* w2  = (const float*)d_in[3];
    const float* w3  = (const float*)d_in[4];
    const float* w4  = (const float*)d_in[5];
    const float* g1  = (const float*)d_in[6];
    const float* b1  = (const float*)d_in[7];
    const float* m1  = (const float*)d_in[8];
    const float* v1  = (const float*)d_in[9];
    const float* g2  = (const float*)d_in[10];
    const float* b2  = (const float*)d_in[11];
    const float* m2  = (const float*)d_in[12];
    const float* v2  = (const float*)d_in[13];
    const float* g3  = (const float*)d_in[14];
    const float* b3  = (const float*)d_in[15];
    const float* m3  = (const float*)d_in[16];
    const float* v3  = (const float*)d_in[17];

    char* ws = (char*)d_ws;
    size_t off = 0;
    auto alloc = [&](size_t bytes) {
        char* p = ws + off;
        off += (bytes + 255) & ~(size_t)255;
        return p;
    };
    float* w1f = (float*)alloc((size_t)C1 * 2 * 9 * 4);
    float* t1  = (float*)alloc((size_t)C1 * 4);
    unsigned short* wp2 = (unsigned short*)alloc((size_t)9 * C1 * C2 * 2);
    float* t2  = (float*)alloc((size_t)C2 * 4);
    unsigned short* wp3 = (unsigned short*)alloc((size_t)9 * C2 * C3 * 2);
    float* t3  = (float*)alloc((size_t)C3 * 4);

    repack_w1<<<(C1 * 2 * 9 + 255) / 256, 256, 0, stream>>>(w1, g1, b1, m1, v1, w1f, t1);
    repack_mfma<C1, C2><<<(9 * C1 * C2 + 255) / 256, 256, 0, stream>>>(w2, g2, b2, m2, v2, wp2, t2);
    repack_mfma<C2, C3><<<(9 * C2 * C3 + 255) / 256, 256, 0, stream>>>(w3, g3, b3, m3, v3, wp3, t3);
    zero_out<<<(B * K * 2 + 255) / 256, 256, 0, stream>>>((float*)d_out);

    fused_all<<<dim3(2, B), 256, 0, stream>>>(x, sig, w1f, t1, wp2, t2, wp3, t3, w4, (float*)d_out);
}